// Round 12
// baseline (94.251 us; speedup 1.0000x reference)
//
#include <hip/hip_runtime.h>

#define BATCH 32
#define I_TOT 4096
#define N_CAP 16
#define K_DIM 128

// pack geometry: 64 chunks x 64 rows (2048 blocks)
#define CCHUNK 64
#define NCH_CS 64
// routing geometry: 64 chunks x 64 rows (2048 blocks, 8 blocks/CU)
#define NRCH 64
#define RROWS 64
// fallback routing: 32 chunks x 128 rows
#define FB_NCHUNK 32
#define FB_RCHUNK 128

// float offsets in ws
#define WS_CS    0                                  // [B][64][128] colsum partials (1 MB)
#define WS_FBWO  262144                             // fallback fp32 wo [B][2048]
#define WS_WOB   327680                             // bf16 wo [B][2048] ushorts (32768 fslots)
#define WS_SP    360448                             // [B][64][2048] s partials (16 MB)
#define WS_PACK  4554752                            // row-major bf16 A-frags (32 MB)
#define WS_PACKT (WS_PACK + 8388608)                // k-major bf16 u^T frags (32 MB)
#define WS_TOTAL_F (WS_PACKT + 8388608)             // ~85.3 MB

typedef __attribute__((ext_vector_type(8))) short bf16x8;
typedef __attribute__((ext_vector_type(4))) float f32x4;

__device__ inline ushort f2bf(float x) {
    unsigned u = __float_as_uint(x);
    u += 0x7FFFu + ((u >> 16) & 1u);   // round-to-nearest-even
    return (ushort)(u >> 16);
}

// ---------------------------------------------------------------------------
// K0: pack u -> row-major bf16 A-frags + k-major u_t frags + colsum partials.
// grid (64, B), block 256 (R7-proven).
// Row-major frag: tiles [b][row>>4][k>>5], lane=(row&15)+16*((k&31)>>3), j=k&7
// K-major frag:   tiles [b][k>>4][i>>5],  lane=(k&15)+16*((i&31)>>3),  j=i&7
__global__ __launch_bounds__(256) void pack_kernel(const float* __restrict__ u,
                                                   float* __restrict__ ws, int do_pack) {
    const int b = blockIdx.y, chunk = blockIdx.x, t = threadIdx.x;
    const int c0 = chunk * CCHUNK;
    ushort* up = (ushort*)(ws + WS_PACK);
    ushort* ut = (ushort*)(ws + WS_PACKT);
    const int k4 = t & 31, rg = t >> 5;

    __shared__ ushort lds_bf[CCHUNK][K_DIM + 8];
    __shared__ __align__(16) float4 red[8][32];

    float4 acc = {0.f, 0.f, 0.f, 0.f};
    #pragma unroll
    for (int m = 0; m < 8; m++) {
        int R = c0 + m * 8 + rg;
        float4 v = *(const float4*)&u[((size_t)b * I_TOT + R) * K_DIM + k4 * 4];
        acc.x += v.x; acc.y += v.y; acc.z += v.z; acc.w += v.w;
        if (do_pack) {
            ushort4 w = { f2bf(v.x), f2bf(v.y), f2bf(v.z), f2bf(v.w) };
            int k = k4 * 4;
            int kt = k >> 5, lane_hi = (k & 31) >> 3, j0 = k & 7;
            size_t off = (((size_t)(b * 256 + (R >> 4)) * 4 + kt) * 64
                          + (R & 15) + (lane_hi << 4)) * 8 + j0;
            *(ushort4*)&up[off] = w;
            *(ushort4*)&lds_bf[m * 8 + rg][k] = w;
        }
    }
    red[rg][k4] = acc;
    __syncthreads();
    if (t < 32) {
        float4 s = red[0][t];
        #pragma unroll
        for (int r = 1; r < 8; r++) {
            float4 v = red[r][t];
            s.x += v.x; s.y += v.y; s.z += v.z; s.w += v.w;
        }
        *(float4*)&ws[WS_CS + ((size_t)(b * NCH_CS + chunk)) * K_DIM + t * 4] = s;
    }

    if (do_pack) {
        __syncthreads();
        #pragma unroll
        for (int q = 0; q < 4; q++) {
            int cc = q * 256 + t;
            int k = cc & 127, io = cc >> 7;      // io 0..7 (8-row octet)
            int ig0 = c0 + io * 8;
            bf16x8 w8;
            #pragma unroll
            for (int j = 0; j < 8; j++) w8[j] = (short)lds_bf[io * 8 + j][k];
            size_t off = ((((size_t)(b * 8 + (k >> 4))) * 128 + (ig0 >> 5)) * 64
                          + (k & 15) + ((io & 3) << 4)) * 8;
            *(bf16x8*)&ut[off] = w8;
        }
    }
}

// ---------------------------------------------------------------------------
// K2: per-(capsule,batch) update. grid (N_CAP, BATCH), block 128.
// mode 0: s from colsum/16; mode 1: s from sp (nch chunks); both -> l2norm + wo.
// mode 2: s from sp -> squash -> out. wo_bf16: write bf16 (big) vs fp32 (fallback).
__global__ __launch_bounds__(128) void update_kernel(const float* __restrict__ W,
                                                     float* __restrict__ ws,
                                                     float* __restrict__ out,
                                                     int mode, int wo_bf16, int nch) {
    const int n = blockIdx.x, b = blockIdx.y, t = threadIdx.x;

    __shared__ float s_n[K_DIM];
    __shared__ float o_s[N_CAP + 4];

    if (mode == 0) {
        const float* cs = ws + WS_CS + (size_t)b * NCH_CS * K_DIM;
        float a = 0.f;
        #pragma unroll 16
        for (int c = 0; c < NCH_CS; c++) a += cs[(size_t)c * K_DIM + t];
        s_n[t] = a * (1.f / 16.f);
    } else {
        const float* sp = ws + WS_SP + (size_t)b * nch * 2048 + n * K_DIM;
        float a = 0.f;
        #pragma unroll 16
        for (int c = 0; c < nch; c++) a += sp[(size_t)c * 2048 + t];
        s_n[t] = a;
    }
    __syncthreads();

    {
        const int d = t >> 3, kseg = t & 7;
        const int col = n * 16 + d;
        float p = 0.f;
        #pragma unroll
        for (int j = 0; j < 16; j++) {
            int k = kseg * 16 + j;
            p += s_n[k] * W[k * 256 + col];
        }
        p += __shfl_xor(p, 1); p += __shfl_xor(p, 2); p += __shfl_xor(p, 4);
        if (kseg == 0) o_s[d] = p;
    }
    __syncthreads();

    float ss = (mode == 2) ? 1e-7f : 0.f;
    #pragma unroll
    for (int d = 0; d < 16; d++) { float v = o_s[d]; ss += v * v; }

    if (mode == 2) {
        if (t < 16) {
            float scale = sqrtf(ss) / (0.5f + ss);
            out[b * 256 + n * 16 + t] = scale * o_s[t];
        }
        return;
    }

    const float inv = rsqrtf(fmaxf(ss, 1e-12f));
    const float4* wrow = (const float4*)(W + t * 256 + n * 16);
    const float4* o4 = (const float4*)o_s;
    float acc = 0.f;
    #pragma unroll
    for (int q = 0; q < 4; q++) {
        float4 w = wrow[q];
        float4 o = o4[q];
        acc += w.x * o.x + w.y * o.y + w.z * o.z + w.w * o.w;
    }
    if (wo_bf16) {
        ((ushort*)(ws + WS_WOB))[(size_t)b * 2048 + n * K_DIM + t] = f2bf(acc * inv);
    } else {
        ws[WS_FBWO + (size_t)b * 2048 + n * K_DIM + t] = acc * inv;
    }
}

// ---------------------------------------------------------------------------
// K3: MFMA routing pass. grid (64, B), block 256 — 64 rows/block, 8 blocks/CU.
// Phase 1: 1 row-tile per wave (4 MFMAs, packed row-major A, bf16 wo B) -> softmax
// -> c_bf. Phase 2: 2 k-tiles per wave (4 MFMAs, k-major u_t A, c B) -> sp.
__global__ __launch_bounds__(256, 8) void routing_mfma(float* __restrict__ ws) {
    const int b = blockIdx.y, chunk = blockIdx.x, t = threadIdx.x;
    const int lane = t & 63, wave = t >> 6;
    const short* up = (const short*)(ws + WS_PACK);
    const short* utp = (const short*)(ws + WS_PACKT);

    __shared__ __align__(16) short wo_bf[N_CAP][136];   // 272B rows (16B multiple)
    __shared__ __align__(16) ushort c_bf[N_CAP][72];    // 144B rows (16B multiple)

    {   // stage bf16 wo: one bf16x8 per thread
        const ushort* wob = (const ushort*)(ws + WS_WOB) + (size_t)b * 2048;
        bf16x8 v = *(const bf16x8*)&wob[t * 8];
        *(bf16x8*)&wo_bf[t >> 4][(t & 15) * 8] = v;
    }
    __syncthreads();

    const int cap = lane & 15, hi = lane >> 4;
    bf16x8 bfrag[4];
    #pragma unroll
    for (int kt = 0; kt < 4; kt++)
        bfrag[kt] = *(const bf16x8*)&wo_bf[cap][kt * 32 + hi * 8];

    // ---- phase 1: one 16-row tile per wave ----
    {
        const int rt_g = chunk * 4 + wave;             // global row-tile 0..255
        f32x4 acc = {0.f, 0.f, 0.f, 0.f};
        const short* abase = up + (((size_t)(b * 256 + rt_g)) * 4) * 512 + lane * 8;
        #pragma unroll
        for (int kt = 0; kt < 4; kt++) {
            bf16x8 a = *(const bf16x8*)(abase + kt * 512);
            acc = __builtin_amdgcn_mfma_f32_16x16x32_bf16(a, bfrag[kt], acc, 0, 0, 0);
        }
        // D layout: col=lane&15 (cap), row=(lane>>4)*4+r (i_local)
        #pragma unroll
        for (int r = 0; r < 4; r++) {
            float v = acc[r];
            float mx = v;
            mx = fmaxf(mx, __shfl_xor(mx, 1)); mx = fmaxf(mx, __shfl_xor(mx, 2));
            mx = fmaxf(mx, __shfl_xor(mx, 4)); mx = fmaxf(mx, __shfl_xor(mx, 8));
            float e = __expf(v - mx);
            float sm = e;
            sm += __shfl_xor(sm, 1); sm += __shfl_xor(sm, 2);
            sm += __shfl_xor(sm, 4); sm += __shfl_xor(sm, 8);
            c_bf[cap][wave * 16 + hi * 4 + r] = f2bf(e / sm);
        }
    }
    __syncthreads();

    // ---- phase 2: k-tiles {2w, 2w+1}, i-chunks 0..1 ----
    f32x4 s0 = {0.f, 0.f, 0.f, 0.f}, s1 = {0.f, 0.f, 0.f, 0.f};
    const size_t ut_b = (size_t)b * 8;
    #pragma unroll
    for (int ic = 0; ic < 2; ic++) {
        bf16x8 bfr = *(const bf16x8*)&c_bf[cap][ic * 32 + hi * 8];
        const size_t tile = (size_t)chunk * 2 + ic;
        const short* ab0 = utp + (((ut_b + wave * 2 + 0) * 128 + tile) * 64 + lane) * 8;
        const short* ab1 = utp + (((ut_b + wave * 2 + 1) * 128 + tile) * 64 + lane) * 8;
        bf16x8 a0 = *(const bf16x8*)ab0;
        bf16x8 a1 = *(const bf16x8*)ab1;
        s0 = __builtin_amdgcn_mfma_f32_16x16x32_bf16(a0, bfr, s0, 0, 0, 0);
        s1 = __builtin_amdgcn_mfma_f32_16x16x32_bf16(a1, bfr, s1, 0, 0, 0);
    }
    // D layout: col=lane&15=cap, row=(lane>>4)*4+r = k_local within 16-k tile
    float* spw = ws + WS_SP + ((size_t)b * NRCH + chunk) * 2048;
    #pragma unroll
    for (int r = 0; r < 4; r++) {
        spw[cap * K_DIM + (wave * 2 + 0) * 16 + hi * 4 + r] = s0[r];
        spw[cap * K_DIM + (wave * 2 + 1) * 16 + hi * 4 + r] = s1[r];
    }
}

// ---------------------------------------------------------------------------
// K3b: fp32 fallback routing if ws too small for the packed buffers.
__global__ __launch_bounds__(256) void routing_fp32(const float* __restrict__ u,
                                                    float* __restrict__ ws) {
    const int b = blockIdx.y, chunk = blockIdx.x, t = threadIdx.x;
    const int i0 = chunk * FB_RCHUNK;

    __shared__ __align__(16) float wo_s[N_CAP][K_DIM];
    __shared__ __align__(16) float c_s[FB_RCHUNK][N_CAP];

    const float* w_o = ws + WS_FBWO + (size_t)b * 2048;
    #pragma unroll
    for (int j = 0; j < 8; j++) {
        int idx = t + j * 256;
        ((float*)wo_s)[idx] = w_o[idx];
    }
    __syncthreads();

    {
        const int row = t >> 1, h = t & 1;
        const float4* upx = (const float4*)(u + ((size_t)b * I_TOT + i0 + row) * K_DIM + h * 64);
        const float4* wp = (const float4*)&wo_s[0][h * 64];
        float logit[16];
        #pragma unroll
        for (int n = 0; n < 16; n++) logit[n] = 0.f;
        #pragma unroll
        for (int q = 0; q < 16; q++) {
            float4 v = upx[q];
            #pragma unroll
            for (int n = 0; n < 16; n++) {
                float4 w = wp[n * 32 + q];
                logit[n] += v.x * w.x + v.y * w.y + v.z * w.z + v.w * w.w;
            }
        }
        #pragma unroll
        for (int n = 0; n < 16; n++) logit[n] += __shfl_xor(logit[n], 1);
        float m = logit[0];
        #pragma unroll
        for (int n = 1; n < 16; n++) m = fmaxf(m, logit[n]);
        float sum = 0.f;
        #pragma unroll
        for (int n = 0; n < 16; n++) { logit[n] = __expf(logit[n] - m); sum += logit[n]; }
        float inv = 1.f / sum;
        float4* crow = (float4*)&c_s[row][h * 8];
        if (h == 0) {
            crow[0] = make_float4(logit[0]*inv, logit[1]*inv, logit[2]*inv, logit[3]*inv);
            crow[1] = make_float4(logit[4]*inv, logit[5]*inv, logit[6]*inv, logit[7]*inv);
        } else {
            crow[0] = make_float4(logit[8]*inv, logit[9]*inv, logit[10]*inv, logit[11]*inv);
            crow[1] = make_float4(logit[12]*inv, logit[13]*inv, logit[14]*inv, logit[15]*inv);
        }
    }
    __syncthreads();

    const int k4 = t & 31, ng = t >> 5;
    float4 a0 = {0.f,0.f,0.f,0.f}, a1 = {0.f,0.f,0.f,0.f};
    const float4* u2 = (const float4*)(u + ((size_t)b * I_TOT + i0) * K_DIM) + k4;
    #pragma unroll 8
    for (int i = 0; i < FB_RCHUNK; i++) {
        float4 v = u2[(size_t)i * 32];
        float2 c2 = *(const float2*)&c_s[i][ng * 2];
        a0.x += v.x * c2.x; a0.y += v.y * c2.x; a0.z += v.z * c2.x; a0.w += v.w * c2.x;
        a1.x += v.x * c2.y; a1.y += v.y * c2.y; a1.z += v.z * c2.y; a1.w += v.w * c2.y;
    }
    float* sp = ws + WS_SP + ((size_t)b * FB_NCHUNK + chunk) * 2048;
    *(float4*)&sp[(ng * 2 + 0) * K_DIM + k4 * 4] = a0;
    *(float4*)&sp[(ng * 2 + 1) * K_DIM + k4 * 4] = a1;
}

// ---------------------------------------------------------------------------
extern "C" void kernel_launch(void* const* d_in, const int* in_sizes, int n_in,
                              void* d_out, int out_size, void* d_ws, size_t ws_size,
                              hipStream_t stream) {
    const float* u = (const float*)d_in[0];   // (32, 4096, 128) f32
    const float* W = (const float*)d_in[1];   // (128, 256) f32
    float* out = (float*)d_out;               // (32, 16, 16) f32
    float* ws = (float*)d_ws;

    const int big = (ws_size >= (size_t)WS_TOTAL_F * 4) ? 1 : 0;
    const int nch = big ? NRCH : FB_NCHUNK;

    pack_kernel<<<dim3(NCH_CS, BATCH), 256, 0, stream>>>(u, ws, big);
    update_kernel<<<dim3(N_CAP, BATCH), 128, 0, stream>>>(W, ws, out, 0, big, nch);

    for (int pass = 0; pass < 3; pass++) {
        if (big) routing_mfma<<<dim3(NRCH, BATCH), 256, 0, stream>>>(ws);
        else     routing_fp32<<<dim3(FB_NCHUNK, BATCH), 256, 0, stream>>>(u, ws);
        update_kernel<<<dim3(N_CAP, BATCH), 128, 0, stream>>>(
            W, ws, out, pass == 2 ? 2 : 1, big, nch);
    }
}

// Round 13
// 83.358 us; speedup vs baseline: 1.1307x; 1.1307x over previous
//
#include <hip/hip_runtime.h>

#define BATCH 32
#define I_TOT 4096
#define N_CAP 16
#define K_DIM 128
#define RCHUNK 128
#define NCHUNK 32          // routing chunks (128 rows each)
#define CCHUNK 64          // pack/colsum chunk rows
#define NCHUNK_CS 64       // colsum partial count

// float-offsets in ws
#define WS_WO    0                         // fallback fp32 wo [B][2048]
#define WS_WOB   65536                     // bf16 wo [B][2048] ushorts (32768 fslots)
#define WS_SP    98304                     // [B][32][2048] f32 (colsum partials [B][64][128] alias; consumed before routing writes)
#define WS_PACK  2195456                   // row-major bf16 A-frags: 16,777,216 shorts
#define WS_PACKT (WS_PACK + 8388608)       // k-major bf16 A-frags (u^T)
#define WS_TOTAL_F (WS_PACKT + 8388608)

typedef __attribute__((ext_vector_type(8))) short bf16x8;
typedef __attribute__((ext_vector_type(4))) float f32x4;

__device__ inline ushort f2bf(float x) {
    unsigned u = __float_as_uint(x);
    u += 0x7FFFu + ((u >> 16) & 1u);   // round-to-nearest-even
    return (ushort)(u >> 16);
}

// ---------------------------------------------------------------------------
// K0: pack u -> row-major bf16 A-frags + k-major u_t frags + colsum partials.
// grid (64, B), block 256 (R7-proven geometry, unchanged).
// Row-major frag: tiles [b][row>>4][k>>5], lane=(row&15)+16*((k&31)>>3), j=k&7
// K-major frag:   tiles [b][k>>4][i>>5],  lane=(k&15)+16*((i&31)>>3),  j=i&7
__global__ __launch_bounds__(256) void pack_kernel(const float* __restrict__ u,
                                                   float* __restrict__ ws, int do_pack) {
    const int b = blockIdx.y, chunk = blockIdx.x, t = threadIdx.x;
    const int c0 = chunk * CCHUNK;
    ushort* up = (ushort*)(ws + WS_PACK);
    ushort* ut = (ushort*)(ws + WS_PACKT);
    const int k4 = t & 31, rg = t >> 5;

    __shared__ ushort lds_bf[CCHUNK][K_DIM + 8];
    __shared__ __align__(16) float4 red[8][32];

    float4 acc = {0.f, 0.f, 0.f, 0.f};
    #pragma unroll
    for (int m = 0; m < 8; m++) {
        int R = c0 + m * 8 + rg;
        float4 v = *(const float4*)&u[((size_t)b * I_TOT + R) * K_DIM + k4 * 4];
        acc.x += v.x; acc.y += v.y; acc.z += v.z; acc.w += v.w;
        if (do_pack) {
            ushort4 w = { f2bf(v.x), f2bf(v.y), f2bf(v.z), f2bf(v.w) };
            int k = k4 * 4;
            int kt = k >> 5, lane_hi = (k & 31) >> 3, j0 = k & 7;
            size_t off = (((size_t)(b * 256 + (R >> 4)) * 4 + kt) * 64
                          + (R & 15) + (lane_hi << 4)) * 8 + j0;
            *(ushort4*)&up[off] = w;
            *(ushort4*)&lds_bf[m * 8 + rg][k] = w;
        }
    }
    red[rg][k4] = acc;
    __syncthreads();
    if (t < 32) {
        float4 s = red[0][t];
        #pragma unroll
        for (int r = 1; r < 8; r++) {
            float4 v = red[r][t];
            s.x += v.x; s.y += v.y; s.z += v.z; s.w += v.w;
        }
        *(float4*)&ws[WS_SP + ((size_t)(b * NCHUNK_CS + chunk)) * K_DIM + t * 4] = s;
    }

    if (do_pack) {
        __syncthreads();
        #pragma unroll
        for (int q = 0; q < 4; q++) {
            int cc = q * 256 + t;
            int k = cc & 127, io = cc >> 7;      // io 0..7 (8-row octet)
            int ig0 = c0 + io * 8;
            bf16x8 w8;
            #pragma unroll
            for (int j = 0; j < 8; j++) w8[j] = (short)lds_bf[io * 8 + j][k];
            size_t off = ((((size_t)(b * 8 + (k >> 4))) * 128 + (ig0 >> 5)) * 64
                          + (k & 15) + ((io & 3) << 4)) * 8;
            *(bf16x8*)&ut[off] = w8;
        }
    }
}

// ---------------------------------------------------------------------------
// K2: per-(capsule,batch) update. grid (N_CAP, BATCH), block 128 (R7-proven).
// mode 0: s from colsum/16; mode 1: s from sp; both -> l2norm + wo.
// mode 2: s from sp -> squash -> out. wo_bf16: bf16 wo (big) vs fp32 (fallback).
__global__ __launch_bounds__(128) void update_kernel(const float* __restrict__ W,
                                                     float* __restrict__ ws,
                                                     float* __restrict__ out,
                                                     int mode, int wo_bf16) {
    const int n = blockIdx.x, b = blockIdx.y, t = threadIdx.x;

    __shared__ float s_n[K_DIM];
    __shared__ float o_s[N_CAP + 4];

    if (mode == 0) {
        const float* sp = ws + WS_SP + (size_t)b * NCHUNK_CS * K_DIM;
        float a = 0.f;
        #pragma unroll 8
        for (int c = 0; c < NCHUNK_CS; c++) a += sp[(size_t)c * K_DIM + t];
        s_n[t] = a * (1.f / 16.f);
    } else {
        const float* sp = ws + WS_SP + (size_t)b * NCHUNK * 2048 + n * K_DIM;
        float a = 0.f;
        #pragma unroll 8
        for (int c = 0; c < NCHUNK; c++) a += sp[(size_t)c * 2048 + t];
        s_n[t] = a;
    }
    __syncthreads();

    {
        const int d = t >> 3, kseg = t & 7;
        const int col = n * 16 + d;
        float p = 0.f;
        #pragma unroll
        for (int j = 0; j < 16; j++) {
            int k = kseg * 16 + j;
            p += s_n[k] * W[k * 256 + col];
        }
        p += __shfl_xor(p, 1); p += __shfl_xor(p, 2); p += __shfl_xor(p, 4);
        if (kseg == 0) o_s[d] = p;
    }
    __syncthreads();

    float ss = (mode == 2) ? 1e-7f : 0.f;
    #pragma unroll
    for (int d = 0; d < 16; d++) { float v = o_s[d]; ss += v * v; }

    if (mode == 2) {
        if (t < 16) {
            float scale = sqrtf(ss) / (0.5f + ss);
            out[b * 256 + n * 16 + t] = scale * o_s[t];
        }
        return;
    }

    const float inv = rsqrtf(fmaxf(ss, 1e-12f));
    const float4* wrow = (const float4*)(W + t * 256 + n * 16);
    const float4* o4 = (const float4*)o_s;
    float acc = 0.f;
    #pragma unroll
    for (int q = 0; q < 4; q++) {
        float4 w = wrow[q];
        float4 o = o4[q];
        acc += w.x * o.x + w.y * o.y + w.z * o.z + w.w * o.w;
    }
    if (wo_bf16) {
        ((ushort*)(ws + WS_WOB))[(size_t)b * 2048 + n * K_DIM + t] = f2bf(acc * inv);
    } else {
        ws[WS_WO + (size_t)b * 2048 + n * K_DIM + t] = acc * inv;
    }
}

// ---------------------------------------------------------------------------
// K3: MFMA routing pass. grid (32, B), block 256 (4 waves, 2 row-tiles each).
// R7 structure; deltas: bf16 wo copy-in (no cvt), ushort4 c_bf store,
// float4 sp stores.
__global__ __launch_bounds__(256) void routing_mfma(float* __restrict__ ws) {
    const int b = blockIdx.y, chunk = blockIdx.x, t = threadIdx.x;
    const int lane = t & 63, wave = t >> 6;
    const short* up = (const short*)(ws + WS_PACK);
    const short* utp = (const short*)(ws + WS_PACKT);

    __shared__ __align__(16) short wo_bf[N_CAP][136];   // 272B rows (16B multiple)
    __shared__ __align__(16) ushort c_bf[N_CAP][136];

    {   // stage bf16 wo: one bf16x8 copy per thread (no conversion)
        const ushort* wob = (const ushort*)(ws + WS_WOB) + (size_t)b * 2048;
        bf16x8 v = *(const bf16x8*)&wob[t * 8];
        *(bf16x8*)&wo_bf[t >> 4][(t & 15) * 8] = v;
    }
    __syncthreads();

    const int cap = lane & 15, hi = lane >> 4;
    bf16x8 bfrag[4];
    #pragma unroll
    for (int kt = 0; kt < 4; kt++)
        bfrag[kt] = *(const bf16x8*)&wo_bf[cap][kt * 32 + hi * 8];

    // ---- phase 1: logits + softmax -> c_bf ----
    #pragma unroll
    for (int rr = 0; rr < 2; rr++) {
        const int rt = wave * 2 + rr;
        const int rt_g = chunk * 8 + rt;
        f32x4 acc = {0.f, 0.f, 0.f, 0.f};
        const short* abase = up + (((size_t)(b * 256 + rt_g)) * 4) * 512 + lane * 8;
        #pragma unroll
        for (int kt = 0; kt < 4; kt++) {
            bf16x8 a = *(const bf16x8*)(abase + kt * 512);
            acc = __builtin_amdgcn_mfma_f32_16x16x32_bf16(a, bfrag[kt], acc, 0, 0, 0);
        }
        // D layout: col=lane&15 (cap), row=(lane>>4)*4+r (i_local)
        ushort4 cw;
        #pragma unroll
        for (int r = 0; r < 4; r++) {
            float v = acc[r];
            float mx = v;
            mx = fmaxf(mx, __shfl_xor(mx, 1)); mx = fmaxf(mx, __shfl_xor(mx, 2));
            mx = fmaxf(mx, __shfl_xor(mx, 4)); mx = fmaxf(mx, __shfl_xor(mx, 8));
            float e = __expf(v - mx);
            float sm = e;
            sm += __shfl_xor(sm, 1); sm += __shfl_xor(sm, 2);
            sm += __shfl_xor(sm, 4); sm += __shfl_xor(sm, 8);
            ((ushort*)&cw)[r] = f2bf(e / sm);
        }
        *(ushort4*)&c_bf[cap][rt * 16 + hi * 4] = cw;   // 8B-aligned: row 272B, ofs mult of 8B
    }
    __syncthreads();

    // ---- phase 2: s[k][cap] via MFMA; wave handles ktiles {2w, 2w+1} ----
    f32x4 s0 = {0.f, 0.f, 0.f, 0.f}, s1 = {0.f, 0.f, 0.f, 0.f};
    const size_t ut_b = ((size_t)b * 8) * 128;
    #pragma unroll
    for (int ic = 0; ic < 4; ic++) {
        bf16x8 bfr = *(const bf16x8*)&c_bf[cap][ic * 32 + hi * 8];
        const short* ab0 = utp + (((ut_b + (size_t)(wave * 2 + 0) * 128) + chunk * 4 + ic) * 64 + lane) * 8;
        const short* ab1 = utp + (((ut_b + (size_t)(wave * 2 + 1) * 128) + chunk * 4 + ic) * 64 + lane) * 8;
        bf16x8 a0 = *(const bf16x8*)ab0;
        bf16x8 a1 = *(const bf16x8*)ab1;
        s0 = __builtin_amdgcn_mfma_f32_16x16x32_bf16(a0, bfr, s0, 0, 0, 0);
        s1 = __builtin_amdgcn_mfma_f32_16x16x32_bf16(a1, bfr, s1, 0, 0, 0);
    }
    // D layout: col=lane&15=cap, row=(lane>>4)*4+r = k_local -> consecutive floats
    float* spw = ws + WS_SP + ((size_t)b * NCHUNK + chunk) * 2048;
    *(f32x4*)&spw[cap * K_DIM + (wave * 2 + 0) * 16 + hi * 4] = s0;
    *(f32x4*)&spw[cap * K_DIM + (wave * 2 + 1) * 16 + hi * 4] = s1;
}

// ---------------------------------------------------------------------------
// K3b: fp32 fallback routing if ws too small for the packed buffers.
__global__ __launch_bounds__(256) void routing_fp32(const float* __restrict__ u,
                                                    float* __restrict__ ws) {
    const int b = blockIdx.y, chunk = blockIdx.x, t = threadIdx.x;
    const int i0 = chunk * RCHUNK;

    __shared__ __align__(16) float wo_s[N_CAP][K_DIM];
    __shared__ __align__(16) float c_s[RCHUNK][N_CAP];

    const float* w_o = ws + WS_WO + (size_t)b * 2048;
    #pragma unroll
    for (int j = 0; j < 8; j++) {
        int idx = t + j * 256;
        ((float*)wo_s)[idx] = w_o[idx];
    }
    __syncthreads();

    {
        const int row = t >> 1, h = t & 1;
        const float4* upx = (const float4*)(u + ((size_t)b * I_TOT + i0 + row) * K_DIM + h * 64);
        const float4* wp = (const float4*)&wo_s[0][h * 64];
        float logit[16];
        #pragma unroll
        for (int n = 0; n < 16; n++) logit[n] = 0.f;
        #pragma unroll
        for (int q = 0; q < 16; q++) {
            float4 v = upx[q];
            #pragma unroll
            for (int n = 0; n < 16; n++) {
                float4 w = wp[n * 32 + q];
                logit[n] += v.x * w.x + v.y * w.y + v.z * w.z + v.w * w.w;
            }
        }
        #pragma unroll
        for (int n = 0; n < 16; n++) logit[n] += __shfl_xor(logit[n], 1);
        float m = logit[0];
        #pragma unroll
        for (int n = 1; n < 16; n++) m = fmaxf(m, logit[n]);
        float sum = 0.f;
        #pragma unroll
        for (int n = 0; n < 16; n++) { logit[n] = __expf(logit[n] - m); sum += logit[n]; }
        float inv = 1.f / sum;
        float4* crow = (float4*)&c_s[row][h * 8];
        if (h == 0) {
            crow[0] = make_float4(logit[0]*inv, logit[1]*inv, logit[2]*inv, logit[3]*inv);
            crow[1] = make_float4(logit[4]*inv, logit[5]*inv, logit[6]*inv, logit[7]*inv);
        } else {
            crow[0] = make_float4(logit[8]*inv, logit[9]*inv, logit[10]*inv, logit[11]*inv);
            crow[1] = make_float4(logit[12]*inv, logit[13]*inv, logit[14]*inv, logit[15]*inv);
        }
    }
    __syncthreads();

    const int k4 = t & 31, ng = t >> 5;
    float4 a0 = {0.f,0.f,0.f,0.f}, a1 = {0.f,0.f,0.f,0.f};
    const float4* u2 = (const float4*)(u + ((size_t)b * I_TOT + i0) * K_DIM) + k4;
    #pragma unroll 8
    for (int i = 0; i < RCHUNK; i++) {
        float4 v = u2[(size_t)i * 32];
        float2 c2 = *(const float2*)&c_s[i][ng * 2];
        a0.x += v.x * c2.x; a0.y += v.y * c2.x; a0.z += v.z * c2.x; a0.w += v.w * c2.x;
        a1.x += v.x * c2.y; a1.y += v.y * c2.y; a1.z += v.z * c2.y; a1.w += v.w * c2.y;
    }
    float* sp = ws + WS_SP + ((size_t)b * NCHUNK + chunk) * 2048;
    *(float4*)&sp[(ng * 2 + 0) * K_DIM + k4 * 4] = a0;
    *(float4*)&sp[(ng * 2 + 1) * K_DIM + k4 * 4] = a1;
}

// ---------------------------------------------------------------------------
extern "C" void kernel_launch(void* const* d_in, const int* in_sizes, int n_in,
                              void* d_out, int out_size, void* d_ws, size_t ws_size,
                              hipStream_t stream) {
    const float* u = (const float*)d_in[0];   // (32, 4096, 128) f32
    const float* W = (const float*)d_in[1];   // (128, 256) f32
    float* out = (float*)d_out;               // (32, 16, 16) f32
    float* ws = (float*)d_ws;

    const int big = (ws_size >= (size_t)WS_TOTAL_F * 4) ? 1 : 0;

    pack_kernel<<<dim3(NCHUNK_CS, BATCH), 256, 0, stream>>>(u, ws, big);
    update_kernel<<<dim3(N_CAP, BATCH), 128, 0, stream>>>(W, ws, out, 0, big);

    for (int pass = 0; pass < 3; pass++) {
        if (big) routing_mfma<<<dim3(NCHUNK, BATCH), 256, 0, stream>>>(ws);
        else     routing_fp32<<<dim3(NCHUNK, BATCH), 256, 0, stream>>>(u, ws);
        update_kernel<<<dim3(N_CAP, BATCH), 128, 0, stream>>>(
            W, ws, out, pass == 2 ? 2 : 1, big);
    }
}